// Round 2
// 825.613 us; speedup vs baseline: 1.0196x; 1.0196x over previous
//
#include <hip/hip_runtime.h>

// NaryDisEmbedding: out[b,f,0:128]  = counts2(x[b,f]) @ emb2   (base-2 digits, 16 of them)
//                   out[b,f,128:256]= counts3(x[b,f]) @ emb3   (base-3 digits, 16 of them)
// x < 50000: base-2 -> popcount; base-3 -> digits 0..9 only (3^10 = 59049), rest fold into c0.
//
// Algebra: sum_k c_k * e_k  ==  16*e0 + c1*(e1-e0) + c2*(e2-e0)   (since c0 = 16 - c1 - c2)
//
// R4/R5: the 10-step base-3 digit loop ran on the scalar unit (v is wave-uniform via s_load),
// and SALU is 1 op/cyc shared per CU -> ~256k cycles/CU vs a 321k-cycle write-floor budget.
// Replace it with a 256-entry LDS LUT: v = q*243 + r (q = v/243 <= 205 < 243, r < 243),
// counts = lut[q] + lut[r] with (n1 | n2<<8) byte-packing (no cross-byte carry: n1,n2 <= 10).
// Per row: 1 magic-div + 2 uniform-address ds_read_u16 (broadcast, conflict-free) + popc.
// (R5 = identical resubmit of R4: that round died to a container-acquisition failure,
//  no measurement was taken, so no code delta is attributable.)

#define ROWS      819200          // 4096 * 200
#define OUT_C     256             // 2 * EMBED_DIM
#define ROWS_PER_WAVE 100         // 819200 / (2048 blocks * 4 waves)

typedef float f32x4 __attribute__((ext_vector_type(4)));

__device__ __forceinline__ void do_row(int v, bool is2,
                                       const f32x4& base_v, const f32x4& d1, const f32x4& d2,
                                       const unsigned short* __restrict__ lut,
                                       float* __restrict__ dst)
{
    const unsigned uv = (unsigned)v;
    const unsigned q  = uv / 243u;                 // magic-multiply, no HW divide
    const unsigned r  = uv - q * 243u;
    const int s  = (int)lut[q] + (int)lut[r];      // n1 = low byte, n2 = high byte
    const int pc = __popc(uv);                     // base-2 ones count (v < 2^16)
    const float f1 = (float)(is2 ? pc : (s & 0xff));
    const float f2 = (float)(s >> 8);              // d2 == 0 on base-2 lanes
    *(f32x4*)dst = base_v + f1 * d1 + f2 * d2;
}

__global__ __launch_bounds__(256) void nary_embed_kernel(
    const int*   __restrict__ x,
    const float* __restrict__ emb2,
    const float* __restrict__ emb3,
    float*       __restrict__ out)
{
    // ---- 256-entry base-3 digit-count LUT: lut[i] = n1(i) | n2(i) << 8 ----
    __shared__ unsigned short lut[256];
    {
        unsigned t = threadIdx.x;                  // exactly 256 threads -> 1 entry each
        int n1 = 0, n2 = 0;
        #pragma unroll
        for (int k = 0; k < 6; ++k) {              // 3^6 = 729 > 255: 6 digits suffice
            const unsigned qq = t / 3u;
            const unsigned rr = t - qq * 3u;
            n1 += (rr == 1u);
            n2 += (rr == 2u);
            t = qq;
        }
        lut[threadIdx.x] = (unsigned short)(n1 | (n2 << 8));
    }
    __syncthreads();

    const int lane = threadIdx.x & 63;
    const int wave = threadIdx.x >> 6;             // 0..3
    const int c4   = lane * 4;                     // channel quad [c4, c4+4)

    // Hoisted per-lane embedding combination registers.
    const bool is2 = (c4 < 128);
    f32x4 e0, e1, d2;
    if (is2) {
        e0 = *(const f32x4*)(emb2 + 0 * 128 + c4);
        e1 = *(const f32x4*)(emb2 + 1 * 128 + c4);
        d2 = (f32x4){0.f, 0.f, 0.f, 0.f};
    } else {
        const int d = c4 - 128;
        e0 = *(const f32x4*)(emb3 + 0 * 128 + d);
        e1 = *(const f32x4*)(emb3 + 1 * 128 + d);
        d2 = *(const f32x4*)(emb3 + 2 * 128 + d) - e0;
    }
    const f32x4 base_v = 16.f * e0;
    const f32x4 d1     = e1 - e0;

    // Each wave owns a contiguous 100-row chunk: 100 KB of output, 400 B of x.
    const int wid = blockIdx.x * 4 + wave;         // 0..8191
    const int*  xp = x + wid * ROWS_PER_WAVE;      // 16B-aligned (400*wid % 16 == 0)
    float*      op = out + (size_t)wid * ROWS_PER_WAVE * OUT_C + c4;

    // 25 macro-iterations: one wave-uniform int4 (s_load_dwordx4) feeds 4 rows.
    int4 cur = *(const int4*)xp;
    #pragma unroll 5
    for (int i = 0; i < ROWS_PER_WAVE / 4; ++i) {
        int4 nxt;
        if (i + 1 < ROWS_PER_WAVE / 4) nxt = *(const int4*)(xp + (i + 1) * 4);
        float* o0 = op + (size_t)(i * 4) * OUT_C;
        do_row(cur.x, is2, base_v, d1, d2, lut, o0 + 0 * OUT_C);
        do_row(cur.y, is2, base_v, d1, d2, lut, o0 + 1 * OUT_C);
        do_row(cur.z, is2, base_v, d1, d2, lut, o0 + 2 * OUT_C);
        do_row(cur.w, is2, base_v, d1, d2, lut, o0 + 3 * OUT_C);
        cur = nxt;
    }
}

extern "C" void kernel_launch(void* const* d_in, const int* in_sizes, int n_in,
                              void* d_out, int out_size, void* d_ws, size_t ws_size,
                              hipStream_t stream) {
    const int*   x    = (const int*)  d_in[0];
    const float* emb2 = (const float*)d_in[1];
    const float* emb3 = (const float*)d_in[2];
    float*       out  = (float*)d_out;

    // 2048 blocks x 4 waves = 8192 waves; 819200 rows / 8192 = exactly 100 rows/wave.
    nary_embed_kernel<<<dim3(2048), dim3(256), 0, stream>>>(x, emb2, emb3, out);
}

// Round 3
// 824.020 us; speedup vs baseline: 1.0216x; 1.0019x over previous
//
#include <hip/hip_runtime.h>

// NaryDisEmbedding: out[b,f,0:128]  = counts2(x[b,f]) @ emb2   (base-2 digits, 16 of them)
//                   out[b,f,128:256]= counts3(x[b,f]) @ emb3   (base-3 digits, 16 of them)
// x < 50000: base-2 -> popcount; base-3 -> digits 0..9 only (3^10 = 59049), rest fold into c0.
//
// Algebra: sum_k c_k * e_k  ==  16*e0 + c1*(e1-e0) + c2*(e2-e0)   (since c0 = 16 - c1 - c2)
//
// R5 result: LUT replaced the 10-step digit loop; kernel ~155us (vs ~195us), ~32k VALU
// cycles/CU vs 321k-cycle write budget -> ALU fully hidden. Remaining 16% gap vs the
// 133us write floor is in the store path.
// R6: output (839 MB) is write-once, never re-read, 25x aggregate L2 -> make all output
// stores non-temporal (nt flag, bypass L2 write-allocate). Fill kernels hit 6.3+ TB/s on
// this same buffer; NT stores should close most of the 155 -> 133us gap.

#define ROWS      819200          // 4096 * 200
#define OUT_C     256             // 2 * EMBED_DIM
#define ROWS_PER_WAVE 100         // 819200 / (2048 blocks * 4 waves)

typedef float f32x4 __attribute__((ext_vector_type(4)));

__device__ __forceinline__ void do_row(int v, bool is2,
                                       const f32x4& base_v, const f32x4& d1, const f32x4& d2,
                                       const unsigned short* __restrict__ lut,
                                       float* __restrict__ dst)
{
    const unsigned uv = (unsigned)v;
    const unsigned q  = uv / 243u;                 // magic-multiply, no HW divide
    const unsigned r  = uv - q * 243u;
    const int s  = (int)lut[q] + (int)lut[r];      // n1 = low byte, n2 = high byte
    const int pc = __popc(uv);                     // base-2 ones count (v < 2^16)
    const float f1 = (float)(is2 ? pc : (s & 0xff));
    const float f2 = (float)(s >> 8);              // d2 == 0 on base-2 lanes
    const f32x4 res = base_v + f1 * d1 + f2 * d2;
    __builtin_nontemporal_store(res, (f32x4*)dst); // nt store: skip L2 write-allocate
}

__global__ __launch_bounds__(256) void nary_embed_kernel(
    const int*   __restrict__ x,
    const float* __restrict__ emb2,
    const float* __restrict__ emb3,
    float*       __restrict__ out)
{
    // ---- 256-entry base-3 digit-count LUT: lut[i] = n1(i) | n2(i) << 8 ----
    __shared__ unsigned short lut[256];
    {
        unsigned t = threadIdx.x;                  // exactly 256 threads -> 1 entry each
        int n1 = 0, n2 = 0;
        #pragma unroll
        for (int k = 0; k < 6; ++k) {              // 3^6 = 729 > 255: 6 digits suffice
            const unsigned qq = t / 3u;
            const unsigned rr = t - qq * 3u;
            n1 += (rr == 1u);
            n2 += (rr == 2u);
            t = qq;
        }
        lut[threadIdx.x] = (unsigned short)(n1 | (n2 << 8));
    }
    __syncthreads();

    const int lane = threadIdx.x & 63;
    const int wave = threadIdx.x >> 6;             // 0..3
    const int c4   = lane * 4;                     // channel quad [c4, c4+4)

    // Hoisted per-lane embedding combination registers.
    const bool is2 = (c4 < 128);
    f32x4 e0, e1, d2;
    if (is2) {
        e0 = *(const f32x4*)(emb2 + 0 * 128 + c4);
        e1 = *(const f32x4*)(emb2 + 1 * 128 + c4);
        d2 = (f32x4){0.f, 0.f, 0.f, 0.f};
    } else {
        const int d = c4 - 128;
        e0 = *(const f32x4*)(emb3 + 0 * 128 + d);
        e1 = *(const f32x4*)(emb3 + 1 * 128 + d);
        d2 = *(const f32x4*)(emb3 + 2 * 128 + d) - e0;
    }
    const f32x4 base_v = 16.f * e0;
    const f32x4 d1     = e1 - e0;

    // Each wave owns a contiguous 100-row chunk: 100 KB of output, 400 B of x.
    const int wid = blockIdx.x * 4 + wave;         // 0..8191
    const int*  xp = x + wid * ROWS_PER_WAVE;      // 16B-aligned (400*wid % 16 == 0)
    float*      op = out + (size_t)wid * ROWS_PER_WAVE * OUT_C + c4;

    // 25 macro-iterations: one wave-uniform int4 (s_load_dwordx4) feeds 4 rows.
    int4 cur = *(const int4*)xp;
    #pragma unroll 5
    for (int i = 0; i < ROWS_PER_WAVE / 4; ++i) {
        int4 nxt;
        if (i + 1 < ROWS_PER_WAVE / 4) nxt = *(const int4*)(xp + (i + 1) * 4);
        float* o0 = op + (size_t)(i * 4) * OUT_C;
        do_row(cur.x, is2, base_v, d1, d2, lut, o0 + 0 * OUT_C);
        do_row(cur.y, is2, base_v, d1, d2, lut, o0 + 1 * OUT_C);
        do_row(cur.z, is2, base_v, d1, d2, lut, o0 + 2 * OUT_C);
        do_row(cur.w, is2, base_v, d1, d2, lut, o0 + 3 * OUT_C);
        cur = nxt;
    }
}

extern "C" void kernel_launch(void* const* d_in, const int* in_sizes, int n_in,
                              void* d_out, int out_size, void* d_ws, size_t ws_size,
                              hipStream_t stream) {
    const int*   x    = (const int*)  d_in[0];
    const float* emb2 = (const float*)d_in[1];
    const float* emb3 = (const float*)d_in[2];
    float*       out  = (float*)d_out;

    // 2048 blocks x 4 waves = 8192 waves; 819200 rows / 8192 = exactly 100 rows/wave.
    nary_embed_kernel<<<dim3(2048), dim3(256), 0, stream>>>(x, emb2, emb3, out);
}